// Round 1
// baseline (83.669 us; speedup 1.0000x reference)
//
#include <hip/hip_runtime.h>
#include <hip/hip_bf16.h>
#include <stdint.h>

// MoEDense: y[b,f] = x[b,:] @ K[t[b]] + bias[t[b]]
// B=8192, D=F=128, T=64, fp32 in/out, int32 idx. Threshold 0.103 abs.
//
// R14 = R13 (69.4us) with the per-block tidx scan replaced by two-phase
// binning through d_ws:
//   - bin_rows: 8192 threads, atomicAdd per-expert counters, scatter row
//     ids into 64 buckets of CAP=192 (same capacity/poison-fail policy
//     as R13; row order within an expert is irrelevant -> absmax 0.03125
//     preserved: per-row k-accumulation order unchanged).
//   - moe_mfma: R13's validated B-prefetch/MFMA/epilogue, but prelude is
//     now one scalar cnt load + 256B row-list read. 3 barriers -> 1.
//     Inactive blocks exit after a single load instead of a 32KB scan.
// Theory: kernel is latency-bound (~29us vs ~2us BW floor); the scan +
// 2 barriers + emit was the head of every block's critical path and 6MB
// of redundant L2 reads (R11/R12's "contention"). Removing it should cut
// moe kernel to ~15-18us -> dur_us ~58-62.

#define D_ 128
#define F_ 128
#define T_ 64
#define TILE_M 64
#define TPE 3
#define CAP (TILE_M * TPE)     // 192 rows/expert capacity (5.7 sigma)
#define LDA 136                // LDS A row stride in shorts (bank-uniform)

typedef __attribute__((ext_vector_type(8))) short short8;
typedef __attribute__((ext_vector_type(4))) float floatx4;

__device__ __forceinline__ int clamp_t(int t) {
    return t < 0 ? 0 : (t > T_ - 1 ? T_ - 1 : t);
}

union frag_u {                 // bf16x2 <-> frag mapping (validated R9-R13)
    short8 s;
    __hip_bfloat162 p[4];
};

// ws layout (ints): [0..63] per-expert counts, [64 .. 64+64*CAP) row ids.
__global__ __launch_bounds__(256) void bin_rows(
    const int* __restrict__ tidx, int* __restrict__ ws)
{
    const int i = blockIdx.x * 256 + threadIdx.x;   // grid 32 -> 8192 rows
    const int t = clamp_t(tidx[i]);
    const int pos = atomicAdd(ws + t, 1);
    if (pos < CAP) ws[T_ + t * CAP + pos] = i;      // overflow rows dropped
}                                                   // -> out poison -> loud fail

__global__ __launch_bounds__(256) void moe_mfma(
    const float* __restrict__ x,     // [8192][128]
    const float* __restrict__ kern,  // [64][128][128]
    const float* __restrict__ bias,  // [64][128]
    const int*   __restrict__ ws,    // binned lists
    float*       __restrict__ out)   // [8192][128]
{
    const int e    = blockIdx.x & 63;           // expert (XCD-friendly:
    const int tb   = blockIdx.x >> 6;           //  tiles e, e+64, e+128 all
    const int m0   = tb * TILE_M;               //  land on XCD e%8)
    const int tid  = threadIdx.x;
    const int wv   = tid >> 6;
    const int lane = tid & 63;
    const int quad = lane >> 4;
    const int l16  = lane & 15;
    const int n0w  = wv * 32;

    int cnt = ws[e];                            // uniform -> s_load
    cnt = cnt > CAP ? CAP : cnt;
    if (m0 >= cnt) return;                      // inactive: one load, out

    __shared__ int slot[TILE_M];
    __shared__ __align__(16) unsigned short A[TILE_M * LDA];

    const int* __restrict__ rl = ws + T_ + e * CAP + m0;

    // Row id for A staging: 4 threads/row share one 4B load (L1 broadcast);
    // no barrier needed before the x gather -> gather starts immediately.
    const int arow = tid >> 2;                  // 0..63
    const int r    = (m0 + arow < cnt) ? rl[arow] : -1;

    if (tid < TILE_M) slot[tid] = (m0 + tid < cnt) ? rl[tid] : -1;

    // ---- PREFETCH: B columns + bias (identical to R13) ----
    const float* Bp = kern + e * (D_ * F_);
    float c0r[4][8], c1r[4][8];
    #pragma unroll
    for (int kc = 0; kc < 4; ++kc) {
        const float* bp = Bp + (kc * 32 + quad * 8) * F_ + n0w + l16;
        #pragma unroll
        for (int j = 0; j < 8; ++j) {
            c0r[kc][j] = bp[j * F_];
            c1r[kc][j] = bp[j * F_ + 16];
        }
    }
    const float bs0 = bias[e * F_ + n0w + l16];
    const float bs1 = bias[e * F_ + n0w + l16 + 16];

    // ---- stage A: 64 rows x 128 cols, fp32 gather -> bf16 LDS ----
    {
        const int c = (tid & 3) * 32;           // 0,32,64,96
        float4 v0 = {0.f,0.f,0.f,0.f}, v1 = v0, v2 = v0, v3 = v0;
        float4 v4 = v0, v5 = v0, v6 = v0, v7 = v0;
        if (r >= 0) {
            const float4* xp = reinterpret_cast<const float4*>(x + r * D_ + c);
            v0 = xp[0]; v1 = xp[1]; v2 = xp[2]; v3 = xp[3];
            v4 = xp[4]; v5 = xp[5]; v6 = xp[6]; v7 = xp[7];
        }
        frag_u h0, h1, h2, h3;
        h0.p[0] = __float22bfloat162_rn({v0.x, v0.y});
        h0.p[1] = __float22bfloat162_rn({v0.z, v0.w});
        h0.p[2] = __float22bfloat162_rn({v1.x, v1.y});
        h0.p[3] = __float22bfloat162_rn({v1.z, v1.w});
        h1.p[0] = __float22bfloat162_rn({v2.x, v2.y});
        h1.p[1] = __float22bfloat162_rn({v2.z, v2.w});
        h1.p[2] = __float22bfloat162_rn({v3.x, v3.y});
        h1.p[3] = __float22bfloat162_rn({v3.z, v3.w});
        h2.p[0] = __float22bfloat162_rn({v4.x, v4.y});
        h2.p[1] = __float22bfloat162_rn({v4.z, v4.w});
        h2.p[2] = __float22bfloat162_rn({v5.x, v5.y});
        h2.p[3] = __float22bfloat162_rn({v5.z, v5.w});
        h3.p[0] = __float22bfloat162_rn({v6.x, v6.y});
        h3.p[1] = __float22bfloat162_rn({v6.z, v6.w});
        h3.p[2] = __float22bfloat162_rn({v7.x, v7.y});
        h3.p[3] = __float22bfloat162_rn({v7.z, v7.w});
        *reinterpret_cast<short8*>(&A[arow * LDA + c])      = h0.s;
        *reinterpret_cast<short8*>(&A[arow * LDA + c + 8])  = h1.s;
        *reinterpret_cast<short8*>(&A[arow * LDA + c + 16]) = h2.s;
        *reinterpret_cast<short8*>(&A[arow * LDA + c + 24]) = h3.s;
    }
    __syncthreads();                            // covers slot[] + A[]

    // ---- MFMA: wave wv -> cols [32wv, 32wv+32); 4 m-subtiles x 2 n ----
    floatx4 acc0[4], acc1[4];
    #pragma unroll
    for (int m = 0; m < 4; ++m) {
        acc0[m] = (floatx4){0.f,0.f,0.f,0.f};
        acc1[m] = (floatx4){0.f,0.f,0.f,0.f};
    }

    #pragma unroll
    for (int kc = 0; kc < 4; ++kc) {
        const int k0 = kc * 32;
        frag_u b0, b1;
        #pragma unroll
        for (int j = 0; j < 4; ++j) {
            b0.p[j] = __float22bfloat162_rn({c0r[kc][2 * j], c0r[kc][2 * j + 1]});
            b1.p[j] = __float22bfloat162_rn({c1r[kc][2 * j], c1r[kc][2 * j + 1]});
        }
        #pragma unroll
        for (int m = 0; m < 4; ++m) {
            const short8 a = *reinterpret_cast<const short8*>(
                &A[(m * 16 + l16) * LDA + k0 + quad * 8]);
            acc0[m] = __builtin_amdgcn_mfma_f32_16x16x32_bf16(a, b0.s, acc0[m], 0, 0, 0);
            acc1[m] = __builtin_amdgcn_mfma_f32_16x16x32_bf16(a, b1.s, acc1[m], 0, 0, 0);
        }
    }

    // ---- epilogue: C row m = msub*16 + quad*4 + reg, col n0w + l16 ----
    #pragma unroll
    for (int m = 0; m < 4; ++m) {
        #pragma unroll
        for (int reg = 0; reg < 4; ++reg) {
            const int mr = m * 16 + quad * 4 + reg;
            if (m0 + mr < cnt) {
                const int rr = slot[mr];
                out[rr * F_ + n0w + l16]      = acc0[m][reg] + bs0;
                out[rr * F_ + n0w + l16 + 16] = acc1[m][reg] + bs1;
            }
        }
    }
}

extern "C" void kernel_launch(void* const* d_in, const int* in_sizes, int n_in,
                              void* d_out, int out_size, void* d_ws, size_t ws_size,
                              hipStream_t stream) {
    const float* x    = (const float*)d_in[0];
    const int*   tidx = (const int*)d_in[1];
    const float* kern = (const float*)d_in[2];
    const float* bias = (const float*)d_in[3];
    float* out = (float*)d_out;
    int* ws = (int*)d_ws;
    (void)ws_size; (void)in_sizes; (void)n_in; (void)out_size;

    // zero the 64 expert counters (graph-capturable), bin, then GEMM
    hipMemsetAsync(ws, 0, T_ * sizeof(int), stream);
    bin_rows<<<8192 / 256, 256, 0, stream>>>(tidx, ws);
    moe_mfma<<<TPE * T_, 256, 0, stream>>>(x, kern, bias, ws, out);
}

// Round 2
// 68.041 us; speedup vs baseline: 1.2297x; 1.2297x over previous
//
#include <hip/hip_runtime.h>
#include <hip/hip_bf16.h>
#include <stdint.h>

// MoEDense: y[b,f] = x[b,:] @ K[t[b]] + bias[t[b]]
// B=8192, D=F=128, T=64, fp32 in/out, int32 idx. Threshold 0.103 abs.
//
// R15: single dispatch again (R14's 3-dispatch chain cost +14us of graph
// node overhead; the fill floor ~41us is harness-side and unconditional).
// Binning is now RANGE-PARTITIONED: block (e, tb) takes rows
// [tb*1024,(tb+1)*1024) with t==e. Row order within an expert is
// irrelevant (each row's k-accumulation is independent and bit-identical
// to R13), so no global rank / cross-block communication is needed.
//   - scan: 4KB/block (one int4/thread) vs R13's 32KB
//   - capacity: Binomial(1024,1/64)=16+-3.97, cap 48 = +8.1 sigma;
//     overflow rows stay poisoned -> loud fail (same policy as R13)
//   - grid 512 = 8 ranges x 64 experts -> 2 blocks/CU = 2 waves/SIMD
//     (R13 had 1/SIMD: zero latency hiding on a fully-cold cache)
//   - XCD locality kept: bx%8 == e%8 for all 8 blocks of expert e
//   - MFMA m-subtiles uniformly skipped when m*16 >= cnt (cnt~16 avg)
// Theory: kernel is latency-bound, not scan-bound (R14 evidence); this
// attacks exposed latency via TLP + shorter prelude in ONE dispatch.
// Predict dur 69.4 -> ~55-62. If >=68: B-prefetch (64 strided scalar
// loads) is the residual -> stage K via LDS wide loads next.

#define D_ 128
#define F_ 128
#define T_ 64
#define TILE_M 48
#define NR_ 8              // row ranges of 1024
#define LDA 136            // LDS A row stride in shorts (bank-uniform)

typedef __attribute__((ext_vector_type(8))) short short8;
typedef __attribute__((ext_vector_type(4))) float floatx4;

__device__ __forceinline__ int clamp_t(int t) {
    return t < 0 ? 0 : (t > T_ - 1 ? T_ - 1 : t);
}

union frag_u {                 // bf16x2 <-> frag mapping (validated R9-R13)
    short8 s;
    __hip_bfloat162 p[4];
};

__global__ __launch_bounds__(256, 2) void moe_fused(
    const float* __restrict__ x,     // [8192][128]
    const int*   __restrict__ tidx,  // [8192]
    const float* __restrict__ kern,  // [64][128][128]
    const float* __restrict__ bias,  // [64][128]
    float*       __restrict__ out)   // [8192][128]
{
    const int e    = blockIdx.x & 63;           // expert (XCD-friendly)
    const int tb   = blockIdx.x >> 6;           // row range 0..7
    const int tid  = threadIdx.x;
    const int wv   = tid >> 6;
    const int lane = tid & 63;
    const int quad = lane >> 4;
    const int l16  = lane & 15;
    const int n0w  = wv * 32;

    __shared__ int wtot[4];
    __shared__ int slot[TILE_M];
    __shared__ __align__(16) unsigned short A[TILE_M * LDA];

    // ---- scan own 1024-row range: ONE int4 per thread ----
    const int4 v = reinterpret_cast<const int4*>(tidx)[tb * 256 + tid];

    // ---- B columns + bias prefetch (independent of scan; in flight early)
    const float* Bp = kern + e * (D_ * F_);
    float c0r[4][8], c1r[4][8];
    #pragma unroll
    for (int kc = 0; kc < 4; ++kc) {
        const float* bp = Bp + (kc * 32 + quad * 8) * F_ + n0w + l16;
        #pragma unroll
        for (int j = 0; j < 8; ++j) {
            c0r[kc][j] = bp[j * F_];
            c1r[kc][j] = bp[j * F_ + 16];
        }
    }
    const float bs0 = bias[e * F_ + n0w + l16];
    const float bs1 = bias[e * F_ + n0w + l16 + 16];

    // ---- within-block rank (this block owns its whole range) ----
    int my = (clamp_t(v.x) == e) + (clamp_t(v.y) == e)
           + (clamp_t(v.z) == e) + (clamp_t(v.w) == e);
    int pre = my;                            // wave inclusive prefix
    #pragma unroll
    for (int d = 1; d < 64; d <<= 1) {
        int u = __shfl_up(pre, d);
        if (lane >= d) pre += u;
    }
    if (lane == 63) wtot[wv] = pre;
    __syncthreads();
    int wbase = 0, cnt = 0;
    #pragma unroll
    for (int w = 0; w < 4; ++w) {
        const int t = wtot[w];
        if (w < wv) wbase += t;
        cnt += t;
    }
    const int base = wbase + pre - my;       // exclusive rank in block
    cnt = cnt > TILE_M ? TILE_M : cnt;       // overflow -> poison -> fail

    // ---- emit matching rows to slot[] ----
    if (my > 0 && base < TILE_M) {
        int run = base;
        const int row0 = tb * 1024 + tid * 4;
        const int tt[4] = { v.x, v.y, v.z, v.w };
        #pragma unroll
        for (int j = 0; j < 4; ++j) {
            if (clamp_t(tt[j]) == e) {
                if (run < TILE_M) slot[run] = row0 + j;
                ++run;
            }
        }
    }
    __syncthreads();

    // ---- stage A: up to 48 rows x 128 cols, fp32 gather -> bf16 LDS ----
    {
        const int arow = tid >> 2;          // 0..63 (4 threads/row)
        const int c    = (tid & 3) * 32;    // 0,32,64,96
        const int r    = (arow < cnt) ? slot[arow] : -1;
        float4 v0 = {0.f,0.f,0.f,0.f}, v1 = v0, v2 = v0, v3 = v0;
        float4 v4 = v0, v5 = v0, v6 = v0, v7 = v0;
        if (r >= 0) {
            const float4* xp = reinterpret_cast<const float4*>(x + r * D_ + c);
            v0 = xp[0]; v1 = xp[1]; v2 = xp[2]; v3 = xp[3];
            v4 = xp[4]; v5 = xp[5]; v6 = xp[6]; v7 = xp[7];
        }
        if (arow < TILE_M) {
            frag_u h0, h1, h2, h3;
            h0.p[0] = __float22bfloat162_rn({v0.x, v0.y});
            h0.p[1] = __float22bfloat162_rn({v0.z, v0.w});
            h0.p[2] = __float22bfloat162_rn({v1.x, v1.y});
            h0.p[3] = __float22bfloat162_rn({v1.z, v1.w});
            h1.p[0] = __float22bfloat162_rn({v2.x, v2.y});
            h1.p[1] = __float22bfloat162_rn({v2.z, v2.w});
            h1.p[2] = __float22bfloat162_rn({v3.x, v3.y});
            h1.p[3] = __float22bfloat162_rn({v3.z, v3.w});
            h2.p[0] = __float22bfloat162_rn({v4.x, v4.y});
            h2.p[1] = __float22bfloat162_rn({v4.z, v4.w});
            h2.p[2] = __float22bfloat162_rn({v5.x, v5.y});
            h2.p[3] = __float22bfloat162_rn({v5.z, v5.w});
            h3.p[0] = __float22bfloat162_rn({v6.x, v6.y});
            h3.p[1] = __float22bfloat162_rn({v6.z, v6.w});
            h3.p[2] = __float22bfloat162_rn({v7.x, v7.y});
            h3.p[3] = __float22bfloat162_rn({v7.z, v7.w});
            *reinterpret_cast<short8*>(&A[arow * LDA + c])      = h0.s;
            *reinterpret_cast<short8*>(&A[arow * LDA + c + 8])  = h1.s;
            *reinterpret_cast<short8*>(&A[arow * LDA + c + 16]) = h2.s;
            *reinterpret_cast<short8*>(&A[arow * LDA + c + 24]) = h3.s;
        }
    }
    __syncthreads();

    // ---- MFMA: wave wv -> cols [32wv,32wv+32); <=3 m-subtiles x 2 n ----
    floatx4 acc0[3], acc1[3];
    #pragma unroll
    for (int m = 0; m < 3; ++m) {
        acc0[m] = (floatx4){0.f,0.f,0.f,0.f};
        acc1[m] = (floatx4){0.f,0.f,0.f,0.f};
    }

    #pragma unroll
    for (int kc = 0; kc < 4; ++kc) {
        const int k0 = kc * 32;
        frag_u b0, b1;
        #pragma unroll
        for (int j = 0; j < 4; ++j) {
            b0.p[j] = __float22bfloat162_rn({c0r[kc][2 * j], c0r[kc][2 * j + 1]});
            b1.p[j] = __float22bfloat162_rn({c1r[kc][2 * j], c1r[kc][2 * j + 1]});
        }
        #pragma unroll
        for (int m = 0; m < 3; ++m) {
            if (m * 16 < cnt) {              // uniform skip of empty subtiles
                const short8 a = *reinterpret_cast<const short8*>(
                    &A[(m * 16 + l16) * LDA + k0 + quad * 8]);
                acc0[m] = __builtin_amdgcn_mfma_f32_16x16x32_bf16(a, b0.s, acc0[m], 0, 0, 0);
                acc1[m] = __builtin_amdgcn_mfma_f32_16x16x32_bf16(a, b1.s, acc1[m], 0, 0, 0);
            }
        }
    }

    // ---- epilogue: row = m*16 + quad*4 + reg, col n0w + l16 (+16) ----
    #pragma unroll
    for (int m = 0; m < 3; ++m) {
        if (m * 16 < cnt) {
            #pragma unroll
            for (int reg = 0; reg < 4; ++reg) {
                const int mr = m * 16 + quad * 4 + reg;
                if (mr < cnt) {
                    const int rr = slot[mr];
                    out[rr * F_ + n0w + l16]      = acc0[m][reg] + bs0;
                    out[rr * F_ + n0w + l16 + 16] = acc1[m][reg] + bs1;
                }
            }
        }
    }
}

extern "C" void kernel_launch(void* const* d_in, const int* in_sizes, int n_in,
                              void* d_out, int out_size, void* d_ws, size_t ws_size,
                              hipStream_t stream) {
    const float* x    = (const float*)d_in[0];
    const int*   tidx = (const int*)d_in[1];
    const float* kern = (const float*)d_in[2];
    const float* bias = (const float*)d_in[3];
    float* out = (float*)d_out;
    (void)d_ws; (void)ws_size; (void)in_sizes; (void)n_in; (void)out_size;

    // single dispatch: 8 ranges x 64 experts = 512 blocks (2 blocks/CU)
    moe_fused<<<NR_ * T_, 256, 0, stream>>>(x, tidx, kern, bias, out);
}

// Round 3
// 68.028 us; speedup vs baseline: 1.2299x; 1.0002x over previous
//
#include <hip/hip_runtime.h>
#include <hip/hip_bf16.h>
#include <stdint.h>

// MoEDense: y[b,f] = x[b,:] @ K[t[b]] + bias[t[b]]
// B=8192, D=F=128, T=64, fp32 in/out, int32 idx. Threshold 0.103 abs.
//
// R16 = R15 (68.0us) scaled for OCCUPANCY. Evidence: R13 (full scan) and
// R15 (range scan, 2x TLP at 2 blocks/CU) differ by only 1.4us -> prelude
// is not the bottleneck; kernel window (~19us vs ~5us of true work) is
// exposed cold-cache latency at 2 waves/SIMD with zero block churn.
//   - grid 1024 = 16 ranges x 512 rows x 64 experts; TILE_M 32
//     (Binom(512,1/64)=8+-2.8, cap 32 = +8.5 sigma; overflow rows stay
//     poisoned -> loud fail, same policy as R13/R15)
//   - __launch_bounds__(256,4): 4 blocks/CU = 4 waves/SIMD. VGPR diet:
//     B converted to bf16 frags ONCE early (32 regs, not 64 fp32
//     re-converted per kc), acc 16 regs (2 m-subtiles), staging 4 float4.
//   - XCD locality kept: bx%8 == e%8 for all 16 blocks of expert e.
//   - Arithmetic per row bit-identical to R15 (same frag maps, k-order)
//     -> absmax must stay 0.03125.
// Predict: VGPR ~190->~110, kernel window 19->12-14, dur 68->63-65.
// If >=67: TLP theory dead -> structural floor (41 fill + ~8 launch +
// ~17 cold exec) -> ROOFLINE next round.

#define D_ 128
#define F_ 128
#define T_ 64
#define TILE_M 32
#define NR_ 16             // row ranges of 512
#define LDA 136            // LDS A row stride in shorts (bank-uniform)

typedef __attribute__((ext_vector_type(8))) short short8;
typedef __attribute__((ext_vector_type(4))) float floatx4;

__device__ __forceinline__ int clamp_t(int t) {
    return t < 0 ? 0 : (t > T_ - 1 ? T_ - 1 : t);
}

union frag_u {                 // bf16x2 <-> frag mapping (validated R9-R15)
    short8 s;
    __hip_bfloat162 p[4];
};

__global__ __launch_bounds__(256, 4) void moe_fused(
    const float* __restrict__ x,     // [8192][128]
    const int*   __restrict__ tidx,  // [8192]
    const float* __restrict__ kern,  // [64][128][128]
    const float* __restrict__ bias,  // [64][128]
    float*       __restrict__ out)   // [8192][128]
{
    const int e    = blockIdx.x & 63;           // expert (XCD-friendly)
    const int tb   = blockIdx.x >> 6;           // row range 0..15
    const int tid  = threadIdx.x;
    const int wv   = tid >> 6;
    const int lane = tid & 63;
    const int quad = lane >> 4;
    const int l16  = lane & 15;
    const int n0w  = wv * 32;

    __shared__ int wtot[4];
    __shared__ int slot[TILE_M];
    __shared__ __align__(16) unsigned short A[TILE_M * LDA];

    // ---- scan own 512-row range: ONE int2 per thread ----
    const int2 v = reinterpret_cast<const int2*>(tidx)[tb * 256 + tid];

    // ---- B columns + bias prefetch (independent; in flight during scan)
    const float* Bp = kern + e * (D_ * F_);
    float c0r[4][8], c1r[4][8];
    #pragma unroll
    for (int kc = 0; kc < 4; ++kc) {
        const float* bp = Bp + (kc * 32 + quad * 8) * F_ + n0w + l16;
        #pragma unroll
        for (int j = 0; j < 8; ++j) {
            c0r[kc][j] = bp[j * F_];
            c1r[kc][j] = bp[j * F_ + 16];
        }
    }
    const float bs0 = bias[e * F_ + n0w + l16];
    const float bs1 = bias[e * F_ + n0w + l16 + 16];

    // ---- within-block rank ----
    int my = (clamp_t(v.x) == e) + (clamp_t(v.y) == e);
    int pre = my;                            // wave inclusive prefix
    #pragma unroll
    for (int d = 1; d < 64; d <<= 1) {
        int u = __shfl_up(pre, d);
        if (lane >= d) pre += u;
    }
    if (lane == 63) wtot[wv] = pre;
    __syncthreads();
    int wbase = 0, cnt = 0;
    #pragma unroll
    for (int w = 0; w < 4; ++w) {
        const int t = wtot[w];
        if (w < wv) wbase += t;
        cnt += t;
    }
    if (cnt == 0) return;                    // uniform; ~0.35 blocks expected
    const int base = wbase + pre - my;       // exclusive rank in block
    cnt = cnt > TILE_M ? TILE_M : cnt;       // overflow -> poison -> fail

    // ---- emit matching rows to slot[] ----
    if (my > 0 && base < TILE_M) {
        int run = base;
        const int row0 = tb * 512 + tid * 2;
        const int tt[2] = { v.x, v.y };
        #pragma unroll
        for (int j = 0; j < 2; ++j) {
            if (clamp_t(tt[j]) == e) {
                if (run < TILE_M) slot[run] = row0 + j;
                ++run;
            }
        }
    }

    // ---- convert B to bf16 frags ONCE (frees 64 fp32 regs -> 32 bf16) ----
    frag_u bf0[4], bf1[4];
    #pragma unroll
    for (int kc = 0; kc < 4; ++kc) {
        #pragma unroll
        for (int j = 0; j < 4; ++j) {
            bf0[kc].p[j] = __float22bfloat162_rn({c0r[kc][2 * j], c0r[kc][2 * j + 1]});
            bf1[kc].p[j] = __float22bfloat162_rn({c1r[kc][2 * j], c1r[kc][2 * j + 1]});
        }
    }
    __syncthreads();

    // ---- stage A: 32 rows x 128 cols, fp32 gather -> bf16 LDS ----
    {
        const int arow = tid >> 3;          // 0..31 (8 threads/row)
        const int c    = (tid & 7) * 16;    // 0,16,...,112
        const int r    = (arow < cnt) ? slot[arow] : -1;
        float4 v0 = {0.f,0.f,0.f,0.f}, v1 = v0, v2 = v0, v3 = v0;
        if (r >= 0) {
            const float4* xp = reinterpret_cast<const float4*>(x + r * D_ + c);
            v0 = xp[0]; v1 = xp[1]; v2 = xp[2]; v3 = xp[3];
        }
        frag_u h0, h1;
        h0.p[0] = __float22bfloat162_rn({v0.x, v0.y});
        h0.p[1] = __float22bfloat162_rn({v0.z, v0.w});
        h0.p[2] = __float22bfloat162_rn({v1.x, v1.y});
        h0.p[3] = __float22bfloat162_rn({v1.z, v1.w});
        h1.p[0] = __float22bfloat162_rn({v2.x, v2.y});
        h1.p[1] = __float22bfloat162_rn({v2.z, v2.w});
        h1.p[2] = __float22bfloat162_rn({v3.x, v3.y});
        h1.p[3] = __float22bfloat162_rn({v3.z, v3.w});
        *reinterpret_cast<short8*>(&A[arow * LDA + c])     = h0.s;
        *reinterpret_cast<short8*>(&A[arow * LDA + c + 8]) = h1.s;
    }
    __syncthreads();

    // ---- MFMA: wave wv -> cols [32wv,32wv+32); <=2 m-subtiles x 2 n ----
    floatx4 acc0[2], acc1[2];
    #pragma unroll
    for (int m = 0; m < 2; ++m) {
        acc0[m] = (floatx4){0.f,0.f,0.f,0.f};
        acc1[m] = (floatx4){0.f,0.f,0.f,0.f};
    }

    #pragma unroll
    for (int kc = 0; kc < 4; ++kc) {
        const int k0 = kc * 32;
        #pragma unroll
        for (int m = 0; m < 2; ++m) {
            if (m * 16 < cnt) {              // uniform skip of empty subtile
                const short8 a = *reinterpret_cast<const short8*>(
                    &A[(m * 16 + l16) * LDA + k0 + quad * 8]);
                acc0[m] = __builtin_amdgcn_mfma_f32_16x16x32_bf16(a, bf0[kc].s, acc0[m], 0, 0, 0);
                acc1[m] = __builtin_amdgcn_mfma_f32_16x16x32_bf16(a, bf1[kc].s, acc1[m], 0, 0, 0);
            }
        }
    }

    // ---- epilogue: row = m*16 + quad*4 + reg, col n0w + l16 (+16) ----
    #pragma unroll
    for (int m = 0; m < 2; ++m) {
        if (m * 16 < cnt) {
            #pragma unroll
            for (int reg = 0; reg < 4; ++reg) {
                const int mr = m * 16 + quad * 4 + reg;
                if (mr < cnt) {
                    const int rr = slot[mr];
                    out[rr * F_ + n0w + l16]      = acc0[m][reg] + bs0;
                    out[rr * F_ + n0w + l16 + 16] = acc1[m][reg] + bs1;
                }
            }
        }
    }
}

extern "C" void kernel_launch(void* const* d_in, const int* in_sizes, int n_in,
                              void* d_out, int out_size, void* d_ws, size_t ws_size,
                              hipStream_t stream) {
    const float* x    = (const float*)d_in[0];
    const int*   tidx = (const int*)d_in[1];
    const float* kern = (const float*)d_in[2];
    const float* bias = (const float*)d_in[3];
    float* out = (float*)d_out;
    (void)d_ws; (void)ws_size; (void)in_sizes; (void)n_in; (void)out_size;

    // single dispatch: 16 ranges x 64 experts = 1024 blocks (4 blocks/CU)
    moe_fused<<<NR_ * T_, 256, 0, stream>>>(x, tidx, kern, bias, out);
}